// Round 13
// baseline (176.286 us; speedup 1.0000x reference)
//
#include <hip/hip_runtime.h>

typedef unsigned short u16;
typedef unsigned int u32;
typedef short bf16x8 __attribute__((ext_vector_type(8)));
typedef float f32x4 __attribute__((ext_vector_type(4)));

// float -> bf16 bits, round-to-nearest-even (inputs never NaN here)
__device__ __forceinline__ u16 f2bf(float f) {
  union { float f; unsigned int u; } a; a.f = f;
  unsigned int r = a.u + 0x7FFFu + ((a.u >> 16) & 1u);
  return (u16)(r >> 16);
}

// ---- K1/K5: Y[o][p] = sum_c W[o*192+c] * X[c*4096+p]; OT out-rows x 2 pixels
// per thread. PX=2: one W ds_read_b128 feeds 8 FMAs (PX=1 was 4) -> halves the
// LDS-pipe cost, which dominated the R12 GEMMs (1.77M reads x 12cyc / 256 CU
// = 34.5us for qkv vs a 5.8us FMA floor).
template <int OT>
__global__ __launch_bounds__(256) void gemm192x2(const float* __restrict__ W,
                                                 const float* __restrict__ X,
                                                 float* __restrict__ Y) {
  __shared__ float wlds[OT * 192];
  int tid = threadIdx.x;
  int p = blockIdx.x * 512 + tid;      // pixel 0; pixel 1 = p + 256
  int o0 = blockIdx.y * OT;
  for (int i = tid; i < OT * 192; i += 256) wlds[i] = W[o0 * 192 + i];
  __syncthreads();
  float acc0[OT], acc1[OT];
  #pragma unroll
  for (int i = 0; i < OT; ++i) { acc0[i] = 0.f; acc1[i] = 0.f; }
  // software-pipelined X loads (both pixels)
  float xa0 = X[0 * 4096 + p],       xa1 = X[1 * 4096 + p];
  float xa2 = X[2 * 4096 + p],       xa3 = X[3 * 4096 + p];
  float xb0 = X[0 * 4096 + p + 256], xb1 = X[1 * 4096 + p + 256];
  float xb2 = X[2 * 4096 + p + 256], xb3 = X[3 * 4096 + p + 256];
  for (int c = 0; c < 192; c += 4) {
    float na0, na1, na2, na3, nb0, nb1, nb2, nb3;
    if (c < 188) {
      na0 = X[(c + 4) * 4096 + p];       na1 = X[(c + 5) * 4096 + p];
      na2 = X[(c + 6) * 4096 + p];       na3 = X[(c + 7) * 4096 + p];
      nb0 = X[(c + 4) * 4096 + p + 256]; nb1 = X[(c + 5) * 4096 + p + 256];
      nb2 = X[(c + 6) * 4096 + p + 256]; nb3 = X[(c + 7) * 4096 + p + 256];
    }
    #pragma unroll
    for (int oo = 0; oo < OT; ++oo) {
      const float4* wv = (const float4*)&wlds[oo * 192 + c];  // broadcast b128
      float4 w4 = *wv;
      acc0[oo] = fmaf(w4.x, xa0, fmaf(w4.y, xa1, fmaf(w4.z, xa2, fmaf(w4.w, xa3, acc0[oo]))));
      acc1[oo] = fmaf(w4.x, xb0, fmaf(w4.y, xb1, fmaf(w4.z, xb2, fmaf(w4.w, xb3, acc1[oo]))));
    }
    xa0 = na0; xa1 = na1; xa2 = na2; xa3 = na3;
    xb0 = nb0; xb1 = nb1; xb2 = nb2; xb3 = nb3;
  }
  #pragma unroll
  for (int oo = 0; oo < OT; ++oo) {
    Y[(size_t)(o0 + oo) * 4096 + p] = acc0[oo];
    Y[(size_t)(o0 + oo) * 4096 + p + 256] = acc1[oo];
  }
}

// ---- K2: depthwise 3x3, pad=1, on [576][64][64] ----
__global__ __launch_bounds__(256) void dwconv3(const float* __restrict__ in,
                                               const float* __restrict__ w,
                                               float* __restrict__ out) {
  int idx = blockIdx.x * 256 + threadIdx.x;  // c*4096 + p
  int c = idx >> 12;
  int p = idx & 4095;
  int y = p >> 6, x = p & 63;
  const float* wc = w + c * 9;
  const float* ic = in + (size_t)c * 4096;
  float s = 0.f;
  #pragma unroll
  for (int i = 0; i < 3; ++i) {
    int yy = y + i - 1;
    if ((unsigned)yy >= 64u) continue;
    #pragma unroll
    for (int j = 0; j < 3; ++j) {
      int xx = x + j - 1;
      if ((unsigned)xx >= 64u) continue;
      s = fmaf(wc[i * 3 + j], ic[yy * 64 + xx], s);
    }
  }
  out[idx] = s;
}

// ---- K3: fused normalize+pack. 256 blocks; per block: 128 pixels of one head.
// Threads 0..127: Q+K normalize+pack ([h][p][32] bf16). Threads 128..255: V pack.
// V key-permutation matches the REGISTER A-frag layout of the transposed-S trick:
// within each 64-key group, key k (b=bit4 of k&31, quad=(k>>2)&3, r=k&3) lands at
// position (k&32) | quad*8 + b*4 + r. Row d==24 = ones -> PV yields denominator.
__global__ __launch_bounds__(256) void nvpack(const float* __restrict__ qkv,
                                              u32* __restrict__ Qh32,
                                              u32* __restrict__ Kh32,
                                              u32* __restrict__ Vt32) {
  __shared__ u32 Ql[128 * 17];
  __shared__ u32 Kl[128 * 17];
  __shared__ u16 Vl[32 * 128];
  int t = threadIdx.x;
  int bid = blockIdx.x;          // 256 blocks
  int h = bid >> 5;
  int p0 = (bid & 31) << 7;      // 128-pixel tile
  u32* Vl32 = (u32*)Vl;
  const float QSC = 0.20412414523193154f * 1.4426950408889634f;  // 24^-0.5 * log2(e)
  if (t < 128) {
    int p = p0 + t;
    float qv[24], kv[24];
    float sq = 0.f, sk = 0.f;
    #pragma unroll
    for (int d = 0; d < 24; ++d) {
      qv[d] = qkv[(size_t)(h * 24 + d) * 4096 + p];
      sq = fmaf(qv[d], qv[d], sq);
    }
    #pragma unroll
    for (int d = 0; d < 24; ++d) {
      kv[d] = qkv[(size_t)(192 + h * 24 + d) * 4096 + p];
      sk = fmaf(kv[d], kv[d], sk);
    }
    float iq = QSC / fmaxf(sqrtf(sq), 1e-12f);  // F.normalize: x / max(||x||, eps)
    float ik = 1.0f / fmaxf(sqrtf(sk), 1e-12f);
    u32* qrow = Ql + t * 17;
    u32* krow = Kl + t * 17;
    #pragma unroll
    for (int j = 0; j < 12; ++j) {
      qrow[j] = ((u32)f2bf(qv[2 * j + 1] * iq) << 16) | f2bf(qv[2 * j] * iq);
      krow[j] = ((u32)f2bf(kv[2 * j + 1] * ik) << 16) | f2bf(kv[2 * j] * ik);
    }
    #pragma unroll
    for (int j = 12; j < 16; ++j) { qrow[j] = 0; krow[j] = 0; }
  } else {
    int tl = t - 128;
    int p = p0 + tl;
    // A-frag key permutation (see header comment)
    int kp = (tl & ~63) | (tl & 32) | (((tl >> 2) & 3) << 3) |
             (((tl >> 4) & 1) << 2) | (tl & 3);
    #pragma unroll
    for (int d = 0; d < 24; ++d)
      Vl[d * 128 + kp] = f2bf(qkv[(size_t)(384 + h * 24 + d) * 4096 + p]);
    Vl[24 * 128 + kp] = 0x3F80;  // bf16 1.0
  }
  for (int i = t; i < 7 * 64; i += 256) Vl32[25 * 64 + i] = 0;  // zero d=25..31
  __syncthreads();
  size_t base = ((size_t)(h << 12) + p0) * 16;
  for (int i = t; i < 2048; i += 256) {
    u32 li = (i >> 4) * 17 + (i & 15);
    Qh32[base + i] = Ql[li];
    Kh32[base + i] = Kl[li];
  }
  for (int i = t; i < 2048; i += 256) {
    int d = i >> 6, c = i & 63;
    Vt32[(((size_t)(h * 32 + d)) << 11) + (p0 >> 1) + c] = Vl32[d * 64 + c];
  }
}

// exp2 each element of two f32x4 (S^T regs r=0..3 = keys quad*4+r), truncate to
// bf16, pack into a PV A-fragment (slots j=0..3 from a, j=4..7 from b).
__device__ __forceinline__ bf16x8 pexp(f32x4 a, f32x4 b) {
  union { u32 u[4]; bf16x8 v; } x;
  u32 a0 = __float_as_uint(__builtin_amdgcn_exp2f(a[0]));
  u32 a1 = __float_as_uint(__builtin_amdgcn_exp2f(a[1]));
  u32 a2 = __float_as_uint(__builtin_amdgcn_exp2f(a[2]));
  u32 a3 = __float_as_uint(__builtin_amdgcn_exp2f(a[3]));
  u32 b0 = __float_as_uint(__builtin_amdgcn_exp2f(b[0]));
  u32 b1 = __float_as_uint(__builtin_amdgcn_exp2f(b[1]));
  u32 b2 = __float_as_uint(__builtin_amdgcn_exp2f(b[2]));
  u32 b3 = __float_as_uint(__builtin_amdgcn_exp2f(b[3]));
  x.u[0] = __builtin_amdgcn_perm(a1, a0, 0x07060302u);
  x.u[1] = __builtin_amdgcn_perm(a3, a2, 0x07060302u);
  x.u[2] = __builtin_amdgcn_perm(b1, b0, 0x07060302u);
  x.u[3] = __builtin_amdgcn_perm(b3, b2, 0x07060302u);
  return x.v;
}

// One 64-key tile, TRANSPOSED-S: S^T = mfma(kf, qf) puts q on lane&15 == the PV
// A-frag m-mapping, so P goes exp2 -> v_perm -> A-frag REGISTERS. No LDS in the
// K-loop.
#define ATTN_TILE(K0, KC, KN, PF)                                               \
  do {                                                                          \
    bf16x8 vf0 = *(const bf16x8*)(Vb + (((size_t)(lo)) << 12) + (K0) + hi * 8);        \
    bf16x8 vf1 = *(const bf16x8*)(Vb + (((size_t)(16 + lo)) << 12) + (K0) + hi * 8);   \
    bf16x8 vf2 = *(const bf16x8*)(Vb + (((size_t)(lo)) << 12) + (K0) + 32 + hi * 8);   \
    bf16x8 vf3 = *(const bf16x8*)(Vb + (((size_t)(16 + lo)) << 12) + (K0) + 32 + hi * 8); \
    if (PF) {                                                                   \
      KN[0] = *(const bf16x8*)(Kb + (((size_t)((K0) + 64 + lo)) << 5) + hi * 8);  \
      KN[1] = *(const bf16x8*)(Kb + (((size_t)((K0) + 80 + lo)) << 5) + hi * 8);  \
      KN[2] = *(const bf16x8*)(Kb + (((size_t)((K0) + 96 + lo)) << 5) + hi * 8);  \
      KN[3] = *(const bf16x8*)(Kb + (((size_t)((K0) + 112 + lo)) << 5) + hi * 8); \
    }                                                                           \
    f32x4 z = {0.f, 0.f, 0.f, 0.f};                                             \
    f32x4 t00 = __builtin_amdgcn_mfma_f32_16x16x32_bf16(KC[0], qf0, z, 0, 0, 0); \
    f32x4 t01 = __builtin_amdgcn_mfma_f32_16x16x32_bf16(KC[1], qf0, z, 0, 0, 0); \
    f32x4 t02 = __builtin_amdgcn_mfma_f32_16x16x32_bf16(KC[2], qf0, z, 0, 0, 0); \
    f32x4 t03 = __builtin_amdgcn_mfma_f32_16x16x32_bf16(KC[3], qf0, z, 0, 0, 0); \
    bf16x8 a00 = pexp(t00, t01);                                                \
    bf16x8 a01 = pexp(t02, t03);                                                \
    o00 = __builtin_amdgcn_mfma_f32_16x16x32_bf16(a00, vf0, o00, 0, 0, 0);      \
    o01 = __builtin_amdgcn_mfma_f32_16x16x32_bf16(a00, vf1, o01, 0, 0, 0);      \
    o00 = __builtin_amdgcn_mfma_f32_16x16x32_bf16(a01, vf2, o00, 0, 0, 0);      \
    o01 = __builtin_amdgcn_mfma_f32_16x16x32_bf16(a01, vf3, o01, 0, 0, 0);      \
    f32x4 t10 = __builtin_amdgcn_mfma_f32_16x16x32_bf16(KC[0], qf1, z, 0, 0, 0); \
    f32x4 t11 = __builtin_amdgcn_mfma_f32_16x16x32_bf16(KC[1], qf1, z, 0, 0, 0); \
    f32x4 t12 = __builtin_amdgcn_mfma_f32_16x16x32_bf16(KC[2], qf1, z, 0, 0, 0); \
    f32x4 t13 = __builtin_amdgcn_mfma_f32_16x16x32_bf16(KC[3], qf1, z, 0, 0, 0); \
    bf16x8 a10 = pexp(t10, t11);                                                \
    bf16x8 a11 = pexp(t12, t13);                                                \
    o10 = __builtin_amdgcn_mfma_f32_16x16x32_bf16(a10, vf0, o10, 0, 0, 0);      \
    o11 = __builtin_amdgcn_mfma_f32_16x16x32_bf16(a10, vf1, o11, 0, 0, 0);      \
    o10 = __builtin_amdgcn_mfma_f32_16x16x32_bf16(a11, vf2, o10, 0, 0, 0);      \
    o11 = __builtin_amdgcn_mfma_f32_16x16x32_bf16(a11, vf3, o11, 0, 0, 0);      \
  } while (0)

// ---- K4: flash attention, register-resident P, zero global intermediates.
// 512-thread blocks (8 waves = 8 K-eighths of 512 keys, shared 32-query group).
// Grid = 8 heads x 128 q-tiles = 1024 blocks. LDS only for epilogue staging.
// No online max (logits bounded +-0.295 after log2e fold).
__global__ __launch_bounds__(512, 4) void attn(const u16* __restrict__ Qh,
                                               const u16* __restrict__ Kh,
                                               const u16* __restrict__ Vt,
                                               float* __restrict__ Y) {
  __shared__ float Sf[8 * 32 * 28];  // 28672 B epilogue staging
  int tid = threadIdx.x;
  int wave = tid >> 6, lane = tid & 63;
  int lo = lane & 15, hi = lane >> 4;
  int b = blockIdx.x;
  int head = b & 7;              // head == XCD (round-robin) -> K/V L2-resident
  int q0 = (b >> 3) << 5;        // 32 queries per block

  const u16* Kb = Kh + ((size_t)head << 17);
  const u16* Vb = Vt + ((size_t)head << 17);

  size_t qrow = (size_t)(head << 12) + q0 + lo;
  bf16x8 qf0 = *(const bf16x8*)(Qh + (qrow << 5) + hi * 8);
  bf16x8 qf1 = *(const bf16x8*)(Qh + ((qrow + 16) << 5) + hi * 8);

  f32x4 o00 = {0.f, 0.f, 0.f, 0.f}, o01 = o00, o10 = o00, o11 = o00;

  int kbase = wave << 9;                        // 512 keys per wave

  bf16x8 kfA[4], kfB[4];
  kfA[0] = *(const bf16x8*)(Kb + (((size_t)(kbase + lo)) << 5) + hi * 8);
  kfA[1] = *(const bf16x8*)(Kb + (((size_t)(kbase + 16 + lo)) << 5) + hi * 8);
  kfA[2] = *(const bf16x8*)(Kb + (((size_t)(kbase + 32 + lo)) << 5) + hi * 8);
  kfA[3] = *(const bf16x8*)(Kb + (((size_t)(kbase + 48 + lo)) << 5) + hi * 8);

  for (int it2 = 0; it2 < 4; ++it2) {           // 8 tiles of 64 keys
    int k0 = kbase + it2 * 128;
    ATTN_TILE(k0, kfA, kfB, 1);
    ATTN_TILE(k0 + 64, kfB, kfA, (it2 < 3));
  }

  // phase 1: stage fp32 C-layout (num cols 0..23, den col 24) into OWN strip.
  int sb = wave * (32 * 28);
  #pragma unroll
  for (int r = 0; r < 4; ++r) {
    int row0 = hi * 4 + r;                      // q rows 0..15 (o00/o01)
    Sf[sb + row0 * 28 + lo] = o00[r];
    if (lo < 8) Sf[sb + row0 * 28 + 16 + lo] = o01[r];
    if (lo == 8) Sf[sb + row0 * 28 + 24] = o01[r];   // ones-row = denominator
    int row1 = 16 + hi * 4 + r;                 // q rows 16..31 (o10/o11)
    Sf[sb + row1 * 28 + lo] = o10[r];
    if (lo < 8) Sf[sb + row1 * 28 + 16 + lo] = o11[r];
    if (lo == 8) Sf[sb + row1 * 28 + 24] = o11[r];
  }
  __syncthreads();
  // phase 2: reduce the 8 K-eighths, normalize, direct coalesced store.
  int q = tid & 31;              // local query row
  int d0 = tid >> 5;             // 0..15
  int base0 = q * 28;
  const int SS = 32 * 28;
  float den = 0.f;
  #pragma unroll
  for (int s = 0; s < 8; ++s) den += Sf[base0 + s * SS + 24];
  float inv = 1.0f / den;
  float* Yh = Y + ((size_t)head * 24) * 4096 + q0 + q;
  float v0 = 0.f;
  #pragma unroll
  for (int s = 0; s < 8; ++s) v0 += Sf[base0 + s * SS + d0];
  Yh[(size_t)d0 * 4096] = v0 * inv;
  if (d0 < 8) {
    float v1 = 0.f;
    #pragma unroll
    for (int s = 0; s < 8; ++s) v1 += Sf[base0 + s * SS + 16 + d0];
    Yh[(size_t)(16 + d0) * 4096] = v1 * inv;
  }
}

extern "C" void kernel_launch(void* const* d_in, const int* in_sizes, int n_in,
                              void* d_out, int out_size, void* d_ws, size_t ws_size,
                              hipStream_t stream) {
  const float* x      = (const float*)d_in[0];  // [192][4096]
  const float* w_qkv  = (const float*)d_in[1];  // [576][192]
  const float* w_dw   = (const float*)d_in[2];  // [576][9]
  const float* w_proj = (const float*)d_in[3];  // [192][192]
  float* out = (float*)d_out;                   // [192][4096] fp32

  char* ws = (char*)d_ws;
  float* qkv    = (float*)(ws);                 // 9437184           (dead after dwconv3)
  float* qkvd   = (float*)(ws + 9437184);       // 9437184           (dead after nvpack)
  u16*   Qh     = (u16*)  (ws + 18874368);      // 2097152
  u16*   Kh     = (u16*)  (ws + 20971520);      // 2097152
  u16*   Vt     = (u16*)  (ws + 23068672);      // 2097152  (end 25165824)
  float* attn_o = (float*)(ws + 13107200);      // 3145728, inside dead qkvd region

  // qkv GEMM: PX=2, OT=6, grid (8,96)=768 blocks = 3 blocks/CU
  gemm192x2<6><<<dim3(8, 96), 256, 0, stream>>>(w_qkv, x, qkv);
  dwconv3<<<dim3(9216), 256, 0, stream>>>(qkv, w_dw, qkvd);
  nvpack<<<dim3(256), 256, 0, stream>>>(qkvd, (u32*)Qh, (u32*)Kh, (u32*)Vt);
  // 1024 blocks x 512 threads; register-resident P
  attn<<<dim3(1024), 512, 0, stream>>>(Qh, Kh, Vt, attn_o);
  // proj GEMM: PX=2, OT=3, grid (8,64)=512 blocks = 2 blocks/CU
  gemm192x2<3><<<dim3(8, 64), 256, 0, stream>>>(w_proj, attn_o, out);
}

// Round 14
// 156.863 us; speedup vs baseline: 1.1238x; 1.1238x over previous
//
#include <hip/hip_runtime.h>

typedef unsigned short u16;
typedef unsigned int u32;
typedef short bf16x8 __attribute__((ext_vector_type(8)));
typedef float f32x4 __attribute__((ext_vector_type(4)));

// float -> bf16 bits, round-to-nearest-even (inputs never NaN here)
__device__ __forceinline__ u16 f2bf(float f) {
  union { float f; unsigned int u; } a; a.f = f;
  unsigned int r = a.u + 0x7FFFu + ((a.u >> 16) & 1u);
  return (u16)(r >> 16);
}

// ---- K1/K5: Y[o][p] = sum_c W[o*192+c] * X[c*4096+p]; OT out-rows x 2 pixels ----
template <int OT>
__global__ __launch_bounds__(256) void gemm192x2(const float* __restrict__ W,
                                                 const float* __restrict__ X,
                                                 float* __restrict__ Y) {
  __shared__ float wlds[OT * 192];
  int tid = threadIdx.x;
  int p = blockIdx.x * 512 + tid;      // pixel 0; pixel 1 = p + 256
  int o0 = blockIdx.y * OT;
  for (int i = tid; i < OT * 192; i += 256) wlds[i] = W[o0 * 192 + i];
  __syncthreads();
  float acc0[OT], acc1[OT];
  #pragma unroll
  for (int i = 0; i < OT; ++i) { acc0[i] = 0.f; acc1[i] = 0.f; }
  float xa0 = X[0 * 4096 + p],       xa1 = X[1 * 4096 + p];
  float xa2 = X[2 * 4096 + p],       xa3 = X[3 * 4096 + p];
  float xb0 = X[0 * 4096 + p + 256], xb1 = X[1 * 4096 + p + 256];
  float xb2 = X[2 * 4096 + p + 256], xb3 = X[3 * 4096 + p + 256];
  for (int c = 0; c < 192; c += 4) {
    float na0, na1, na2, na3, nb0, nb1, nb2, nb3;
    if (c < 188) {
      na0 = X[(c + 4) * 4096 + p];       na1 = X[(c + 5) * 4096 + p];
      na2 = X[(c + 6) * 4096 + p];       na3 = X[(c + 7) * 4096 + p];
      nb0 = X[(c + 4) * 4096 + p + 256]; nb1 = X[(c + 5) * 4096 + p + 256];
      nb2 = X[(c + 6) * 4096 + p + 256]; nb3 = X[(c + 7) * 4096 + p + 256];
    }
    #pragma unroll
    for (int oo = 0; oo < OT; ++oo) {
      float4 w4 = *(const float4*)&wlds[oo * 192 + c];  // broadcast b128
      acc0[oo] = fmaf(w4.x, xa0, fmaf(w4.y, xa1, fmaf(w4.z, xa2, fmaf(w4.w, xa3, acc0[oo]))));
      acc1[oo] = fmaf(w4.x, xb0, fmaf(w4.y, xb1, fmaf(w4.z, xb2, fmaf(w4.w, xb3, acc1[oo]))));
    }
    xa0 = na0; xa1 = na1; xa2 = na2; xa3 = na3;
    xb0 = nb0; xb1 = nb1; xb2 = nb2; xb3 = nb3;
  }
  #pragma unroll
  for (int oo = 0; oo < OT; ++oo) {
    Y[(size_t)(o0 + oo) * 4096 + p] = acc0[oo];
    Y[(size_t)(o0 + oo) * 4096 + p + 256] = acc1[oo];
  }
}

// ---- K2: depthwise 3x3, pad=1, on [576][64][64] ----
__global__ __launch_bounds__(256) void dwconv3(const float* __restrict__ in,
                                               const float* __restrict__ w,
                                               float* __restrict__ out) {
  int idx = blockIdx.x * 256 + threadIdx.x;  // c*4096 + p
  int c = idx >> 12;
  int p = idx & 4095;
  int y = p >> 6, x = p & 63;
  const float* wc = w + c * 9;
  const float* ic = in + (size_t)c * 4096;
  float s = 0.f;
  #pragma unroll
  for (int i = 0; i < 3; ++i) {
    int yy = y + i - 1;
    if ((unsigned)yy >= 64u) continue;
    #pragma unroll
    for (int j = 0; j < 3; ++j) {
      int xx = x + j - 1;
      if ((unsigned)xx >= 64u) continue;
      s = fmaf(wc[i * 3 + j], ic[yy * 64 + xx], s);
    }
  }
  out[idx] = s;
}

// ---- K3: fused normalize+pack. 256 blocks; per block: 128 pixels of one head.
// Threads 0..127: Q+K normalize+pack ([h][p][32] bf16). Threads 128..255: V pack.
// V key-permutation matches the REGISTER A-frag layout of the transposed-S trick:
// within each 64-key group, key k (b=bit4 of k&31, quad=(k>>2)&3, r=k&3) lands at
// position (k&32) | quad*8 + b*4 + r. Row d==24 = ones -> PV yields denominator.
__global__ __launch_bounds__(256) void nvpack(const float* __restrict__ qkv,
                                              u32* __restrict__ Qh32,
                                              u32* __restrict__ Kh32,
                                              u32* __restrict__ Vt32) {
  __shared__ u32 Ql[128 * 17];
  __shared__ u32 Kl[128 * 17];
  __shared__ u16 Vl[32 * 128];
  int t = threadIdx.x;
  int bid = blockIdx.x;          // 256 blocks
  int h = bid >> 5;
  int p0 = (bid & 31) << 7;      // 128-pixel tile
  u32* Vl32 = (u32*)Vl;
  const float QSC = 0.20412414523193154f * 1.4426950408889634f;  // 24^-0.5 * log2(e)
  if (t < 128) {
    int p = p0 + t;
    float qv[24], kv[24];
    float sq = 0.f, sk = 0.f;
    #pragma unroll
    for (int d = 0; d < 24; ++d) {
      qv[d] = qkv[(size_t)(h * 24 + d) * 4096 + p];
      sq = fmaf(qv[d], qv[d], sq);
    }
    #pragma unroll
    for (int d = 0; d < 24; ++d) {
      kv[d] = qkv[(size_t)(192 + h * 24 + d) * 4096 + p];
      sk = fmaf(kv[d], kv[d], sk);
    }
    float iq = QSC / fmaxf(sqrtf(sq), 1e-12f);  // F.normalize: x / max(||x||, eps)
    float ik = 1.0f / fmaxf(sqrtf(sk), 1e-12f);
    u32* qrow = Ql + t * 17;
    u32* krow = Kl + t * 17;
    #pragma unroll
    for (int j = 0; j < 12; ++j) {
      qrow[j] = ((u32)f2bf(qv[2 * j + 1] * iq) << 16) | f2bf(qv[2 * j] * iq);
      krow[j] = ((u32)f2bf(kv[2 * j + 1] * ik) << 16) | f2bf(kv[2 * j] * ik);
    }
    #pragma unroll
    for (int j = 12; j < 16; ++j) { qrow[j] = 0; krow[j] = 0; }
  } else {
    int tl = t - 128;
    int p = p0 + tl;
    // A-frag key permutation (see header comment)
    int kp = (tl & ~63) | (tl & 32) | (((tl >> 2) & 3) << 3) |
             (((tl >> 4) & 1) << 2) | (tl & 3);
    #pragma unroll
    for (int d = 0; d < 24; ++d)
      Vl[d * 128 + kp] = f2bf(qkv[(size_t)(384 + h * 24 + d) * 4096 + p]);
    Vl[24 * 128 + kp] = 0x3F80;  // bf16 1.0
  }
  for (int i = t; i < 7 * 64; i += 256) Vl32[25 * 64 + i] = 0;  // zero d=25..31
  __syncthreads();
  size_t base = ((size_t)(h << 12) + p0) * 16;
  for (int i = t; i < 2048; i += 256) {
    u32 li = (i >> 4) * 17 + (i & 15);
    Qh32[base + i] = Ql[li];
    Kh32[base + i] = Kl[li];
  }
  for (int i = t; i < 2048; i += 256) {
    int d = i >> 6, c = i & 63;
    Vt32[(((size_t)(h * 32 + d)) << 11) + (p0 >> 1) + c] = Vl32[d * 64 + c];
  }
}

// exp2 each element of two f32x4 (S^T regs r=0..3 = keys quad*4+r), truncate to
// bf16, pack into a PV A-fragment (slots j=0..3 from a, j=4..7 from b).
__device__ __forceinline__ bf16x8 pexp(f32x4 a, f32x4 b) {
  union { u32 u[4]; bf16x8 v; } x;
  u32 a0 = __float_as_uint(__builtin_amdgcn_exp2f(a[0]));
  u32 a1 = __float_as_uint(__builtin_amdgcn_exp2f(a[1]));
  u32 a2 = __float_as_uint(__builtin_amdgcn_exp2f(a[2]));
  u32 a3 = __float_as_uint(__builtin_amdgcn_exp2f(a[3]));
  u32 b0 = __float_as_uint(__builtin_amdgcn_exp2f(b[0]));
  u32 b1 = __float_as_uint(__builtin_amdgcn_exp2f(b[1]));
  u32 b2 = __float_as_uint(__builtin_amdgcn_exp2f(b[2]));
  u32 b3 = __float_as_uint(__builtin_amdgcn_exp2f(b[3]));
  x.u[0] = __builtin_amdgcn_perm(a1, a0, 0x07060302u);
  x.u[1] = __builtin_amdgcn_perm(a3, a2, 0x07060302u);
  x.u[2] = __builtin_amdgcn_perm(b1, b0, 0x07060302u);
  x.u[3] = __builtin_amdgcn_perm(b3, b2, 0x07060302u);
  return x.v;
}

// ---- K4: flash attention, register-resident P, 4 Q-frags/wave (64 q), zero
// global intermediates. 512-thread blocks (8 waves = 8 K-eighths of 512 keys).
// Grid = 8 heads x 64 q-groups = 512 blocks. Per 64-key tile: 16 QK + 16 PV
// MFMAs, 4 independent S->exp->PV chains (R4 showed 1.74x from 1->2 frags; all
// 2-frag variants R4/R9/R11/R12/R13 plateau 50-54us). K/V single-buffered at
// tile top (keeps peak VGPR ~112 < 128 cap; dbuf would spill per R10 lesson).
__global__ __launch_bounds__(512, 4) void attn(const u16* __restrict__ Qh,
                                               const u16* __restrict__ Kh,
                                               const u16* __restrict__ Vt,
                                               float* __restrict__ Y) {
  __shared__ float Sf[8 * 64 * 28];  // 57344 B epilogue staging
  int tid = threadIdx.x;
  int wave = tid >> 6, lane = tid & 63;
  int lo = lane & 15, hi = lane >> 4;
  int b = blockIdx.x;
  int head = b & 7;              // head == XCD (round-robin) -> K/V L2-resident
  int q0 = (b >> 3) << 6;        // 64 queries per block

  const u16* Kb = Kh + ((size_t)head << 17);
  const u16* Vb = Vt + ((size_t)head << 17);

  size_t qrow = (size_t)(head << 12) + q0 + lo;
  bf16x8 qf[4];
  #pragma unroll
  for (int f = 0; f < 4; ++f)
    qf[f] = *(const bf16x8*)(Qh + ((qrow + f * 16) << 5) + hi * 8);

  f32x4 zz = {0.f, 0.f, 0.f, 0.f};
  f32x4 oA[4], oB[4];
  #pragma unroll
  for (int f = 0; f < 4; ++f) { oA[f] = zz; oB[f] = zz; }

  int kbase = wave << 9;                        // 512 keys per wave

  for (int it = 0; it < 8; ++it) {              // 8 tiles of 64 keys
    int k0 = kbase + it * 64;
    bf16x8 kf[4], vf[4];
    #pragma unroll
    for (int j = 0; j < 4; ++j)
      kf[j] = *(const bf16x8*)(Kb + (((size_t)(k0 + j * 16 + lo)) << 5) + hi * 8);
    vf[0] = *(const bf16x8*)(Vb + (((size_t)(lo)) << 12) + k0 + hi * 8);
    vf[1] = *(const bf16x8*)(Vb + (((size_t)(16 + lo)) << 12) + k0 + hi * 8);
    vf[2] = *(const bf16x8*)(Vb + (((size_t)(lo)) << 12) + k0 + 32 + hi * 8);
    vf[3] = *(const bf16x8*)(Vb + (((size_t)(16 + lo)) << 12) + k0 + 32 + hi * 8);
    #pragma unroll
    for (int f = 0; f < 4; ++f) {
      f32x4 t0 = __builtin_amdgcn_mfma_f32_16x16x32_bf16(kf[0], qf[f], zz, 0, 0, 0);
      f32x4 t1 = __builtin_amdgcn_mfma_f32_16x16x32_bf16(kf[1], qf[f], zz, 0, 0, 0);
      f32x4 t2 = __builtin_amdgcn_mfma_f32_16x16x32_bf16(kf[2], qf[f], zz, 0, 0, 0);
      f32x4 t3 = __builtin_amdgcn_mfma_f32_16x16x32_bf16(kf[3], qf[f], zz, 0, 0, 0);
      bf16x8 a0 = pexp(t0, t1);
      bf16x8 a1 = pexp(t2, t3);
      oA[f] = __builtin_amdgcn_mfma_f32_16x16x32_bf16(a0, vf[0], oA[f], 0, 0, 0);
      oB[f] = __builtin_amdgcn_mfma_f32_16x16x32_bf16(a0, vf[1], oB[f], 0, 0, 0);
      oA[f] = __builtin_amdgcn_mfma_f32_16x16x32_bf16(a1, vf[2], oA[f], 0, 0, 0);
      oB[f] = __builtin_amdgcn_mfma_f32_16x16x32_bf16(a1, vf[3], oB[f], 0, 0, 0);
    }
  }

  // phase 1: stage fp32 C-layout (num cols 0..23, den col 24) into OWN strip.
  int sb = wave * (64 * 28);
  #pragma unroll
  for (int f = 0; f < 4; ++f) {
    #pragma unroll
    for (int r = 0; r < 4; ++r) {
      int row = f * 16 + hi * 4 + r;
      Sf[sb + row * 28 + lo] = oA[f][r];
      if (lo < 8) Sf[sb + row * 28 + 16 + lo] = oB[f][r];
      if (lo == 8) Sf[sb + row * 28 + 24] = oB[f][r];   // ones-row = denominator
    }
  }
  __syncthreads();
  // phase 2: reduce the 8 K-eighths, normalize, direct coalesced store.
  int q = tid & 63;              // local query row
  int d0 = tid >> 6;             // 0..7
  int base0 = q * 28;
  const int SS = 64 * 28;
  float den = 0.f;
  #pragma unroll
  for (int s = 0; s < 8; ++s) den += Sf[base0 + s * SS + 24];
  float inv = 1.0f / den;
  float* Yh = Y + ((size_t)head * 24) * 4096 + q0 + q;
  #pragma unroll
  for (int dp = 0; dp < 3; ++dp) {
    int dd = dp * 8 + d0;
    float v = 0.f;
    #pragma unroll
    for (int s = 0; s < 8; ++s) v += Sf[base0 + s * SS + dd];
    Yh[(size_t)dd * 4096] = v * inv;
  }
}

extern "C" void kernel_launch(void* const* d_in, const int* in_sizes, int n_in,
                              void* d_out, int out_size, void* d_ws, size_t ws_size,
                              hipStream_t stream) {
  const float* x      = (const float*)d_in[0];  // [192][4096]
  const float* w_qkv  = (const float*)d_in[1];  // [576][192]
  const float* w_dw   = (const float*)d_in[2];  // [576][9]
  const float* w_proj = (const float*)d_in[3];  // [192][192]
  float* out = (float*)d_out;                   // [192][4096] fp32

  char* ws = (char*)d_ws;
  float* qkv    = (float*)(ws);                 // 9437184           (dead after dwconv3)
  float* qkvd   = (float*)(ws + 9437184);       // 9437184           (dead after nvpack)
  u16*   Qh     = (u16*)  (ws + 18874368);      // 2097152
  u16*   Kh     = (u16*)  (ws + 20971520);      // 2097152
  u16*   Vt     = (u16*)  (ws + 23068672);      // 2097152  (end 25165824)
  float* attn_o = (float*)(ws + 13107200);      // 3145728, inside dead qkvd region

  // qkv GEMM: PX=2, OT=6, grid (8,96)=768 blocks = 3 blocks/CU
  gemm192x2<6><<<dim3(8, 96), 256, 0, stream>>>(w_qkv, x, qkv);
  dwconv3<<<dim3(9216), 256, 0, stream>>>(qkv, w_dw, qkvd);
  nvpack<<<dim3(256), 256, 0, stream>>>(qkvd, (u32*)Qh, (u32*)Kh, (u32*)Vt);
  // 512 blocks x 512 threads; 4 q-frags/wave, register-resident P
  attn<<<dim3(512), 512, 0, stream>>>(Qh, Kh, Vt, attn_o);
  // proj GEMM: PX=2, OT=3, grid (8,64)=512 blocks = 2 blocks/CU
  gemm192x2<3><<<dim3(8, 64), 256, 0, stream>>>(w_proj, attn_o, out);
}